// Round 9
// baseline (97.117 us; speedup 1.0000x reference)
//
#include <hip/hip_runtime.h>

#define NQ 10

#if __has_builtin(__builtin_amdgcn_permlane16_swap)
#define HAVE_PLSWAP 1
#endif

// ---------- cross-lane helpers ----------
// lx<M>: value from lane^M.
//   1,2 : DPP quad_perm                          (VALU)
//   4   : DPP half_mirror(xor7) + quad_perm xor3 (2x VALU)
//   8   : DPP row_ror:8                          (VALU)
//   16  : ds_swizzle (readout WHT only)
//   32  : __shfl_xor (readout WHT only)
template<int M>
__device__ __forceinline__ float lx(float v) {
    if constexpr (M == 1)
        return __int_as_float(__builtin_amdgcn_mov_dpp(__float_as_int(v), 0xB1, 0xF, 0xF, true));
    else if constexpr (M == 2)
        return __int_as_float(__builtin_amdgcn_mov_dpp(__float_as_int(v), 0x4E, 0xF, 0xF, true));
    else if constexpr (M == 4) {
        int t = __builtin_amdgcn_mov_dpp(__float_as_int(v), 0x141, 0xF, 0xF, true); // xor7
        return __int_as_float(__builtin_amdgcn_mov_dpp(t, 0x1B, 0xF, 0xF, true));   // xor3
    } else if constexpr (M == 8)
        return __int_as_float(__builtin_amdgcn_mov_dpp(__float_as_int(v), 0x128, 0xF, 0xF, true));
    else if constexpr (M == 16)
        return __int_as_float(__builtin_amdgcn_ds_swizzle(__float_as_int(v), (16 << 10) | 0x1F));
    else
        return __shfl_xor(v, M, 64);
}

template<int M>
__device__ __forceinline__ float2 lx2(float2 v) {
    return make_float2(lx<M>(v.x), lx<M>(v.y));
}

// xch<M> (M=16,32): both values fetched from lane^M via DOUBLE permlane swap
// (direction-invariant; verified R6).
template<int M>
__device__ __forceinline__ void xch(float& a, float& b) {
#ifdef HAVE_PLSWAP
    if constexpr (M == 16) {
        auto r1 = __builtin_amdgcn_permlane16_swap(__float_as_uint(a), __float_as_uint(b), false, false);
        auto r2 = __builtin_amdgcn_permlane16_swap(r1[1], r1[0], false, false);
        a = __uint_as_float(r2[0]);
        b = __uint_as_float(r2[1]);
    } else {
        auto r1 = __builtin_amdgcn_permlane32_swap(__float_as_uint(a), __float_as_uint(b), false, false);
        auto r2 = __builtin_amdgcn_permlane32_swap(r1[1], r1[0], false, false);
        a = __uint_as_float(r2[0]);
        b = __uint_as_float(r2[1]);
    }
#else
    a = lx<M>(a);
    b = lx<M>(b);
#endif
}

__device__ __forceinline__ float2 cmul(float2 a, float2 b) {
    return make_float2(a.x * b.x - a.y * b.y, a.x * b.y + a.y * b.x);
}

__device__ __forceinline__ float2 bperm2(int addr, float2 v) {
    float2 r;
    r.x = __int_as_float(__builtin_amdgcn_ds_bpermute(addr, __float_as_int(v.x)));
    r.y = __int_as_float(__builtin_amdgcn_ds_bpermute(addr, __float_as_int(v.y)));
    return r;
}

// ---------- gates on an 8-reg half-state ----------
template<int M>
__device__ __forceinline__ void ry_lane(float2 st[8], int lane, float c, float s) {
    const float cB = (lane & M) ? s : -s;
#pragma unroll
    for (int r = 0; r < 8; ++r) {
        float2 part = lx2<M>(st[r]);
        st[r].x = c * st[r].x + cB * part.x;
        st[r].y = c * st[r].y + cB * part.y;
    }
}

template<int M>
__device__ __forceinline__ void ry_lane_x(float2 st[8], int lane, float c, float s) {
    const float cB = (lane & M) ? s : -s;
#pragma unroll
    for (int r = 0; r < 8; r += 2) {
        float pax = st[r].x, pay = st[r].y, pbx = st[r + 1].x, pby = st[r + 1].y;
        xch<M>(pax, pbx);
        xch<M>(pay, pby);
        st[r].x     = c * st[r].x     + cB * pax;
        st[r].y     = c * st[r].y     + cB * pay;
        st[r + 1].x = c * st[r + 1].x + cB * pbx;
        st[r + 1].y = c * st[r + 1].y + cB * pby;
    }
}

template<int RB>
__device__ __forceinline__ void ry_reg(float2 st[8], float c, float s) {
#pragma unroll
    for (int r = 0; r < 8; ++r) {
        if (r & RB) continue;
        float2 a0 = st[r], a1 = st[r | RB];
        st[r].x = c * a0.x - s * a1.x;
        st[r].y = c * a0.y - s * a1.y;
        st[r | RB].x = s * a0.x + c * a1.x;
        st[r | RB].y = s * a0.y + c * a1.y;
    }
}

// cross-wave exchange buffer helpers (stride 16 floats per thread)
__device__ __forceinline__ void xw_write(const float2 st[8], float* buf, int tid) {
    float4* row = (float4*)(buf + tid * 16);
#pragma unroll
    for (int k = 0; k < 4; ++k)
        row[k] = make_float4(st[2 * k].x, st[2 * k].y, st[2 * k + 1].x, st[2 * k + 1].y);
}
__device__ __forceinline__ void xw_read(float2 p[8], const float* buf, int ptid) {
    const float4* row = (const float4*)(buf + ptid * 16);
#pragma unroll
    for (int k = 0; k < 4; ++k) {
        float4 v = row[k];
        p[2 * k]     = make_float2(v.x, v.y);
        p[2 * k + 1] = make_float2(v.z, v.w);
    }
}

__device__ __forceinline__ float wht64(float v, int lane) {
    float t;
    t = lx<1>(v);  v = (lane & 1)  ? (t - v) : (v + t);
    t = lx<2>(v);  v = (lane & 2)  ? (t - v) : (v + t);
    t = lx<4>(v);  v = (lane & 4)  ? (t - v) : (v + t);
    t = lx<8>(v);  v = (lane & 8)  ? (t - v) : (v + t);
    t = lx<16>(v); v = (lane & 16) ? (t - v) : (v + t);
    t = lx<32>(v); v = (lane & 32) ? (t - v) : (v + t);
    return v;
}

// ---------- main kernel: TWO waves per batch sample ----------
// State index s = (lane<<4) | (wid<<3) | r.
// Qubit q <-> state bit 9-q: q0..q5 -> lane masks 32..1, q6 -> wave bit,
// q7,q8,q9 -> reg bits 4,2,1.
__global__ __launch_bounds__(128, 8)
void pqc_kernel(const float* __restrict__ x,
                const float* __restrict__ params,
                float* __restrict__ out, int B) {
    const int tid  = threadIdx.x;
    const int lane = tid & 63;
    const int wid  = tid >> 6;
    const int b    = blockIdx.x;

    __shared__ float buf[128 * 16];   // 8 KB cross-wave exchange

    // ---- encoding + ENTIRE layer 0 (RY+RZ) folded into a product state ----
    const float* xb = x + (long)b * NQ;
    const float* p0 = params;
    float a0,b0,a1,b1,a2,b2,a3,b3,a4,b4,a5,b5,a6,b6,a7,b7,a8,b8,a9,b9;
    float cz0,sz0,cz1,sz1,cz2,sz2,cz3,sz3,cz4,sz4,cz5,sz5,cz6,sz6,cz7,sz7,cz8,sz8,cz9,sz9;
    __sincosf(0.5f * (xb[0] + p0[0]), &b0, &a0);
    __sincosf(0.5f * (xb[1] + p0[1]), &b1, &a1);
    __sincosf(0.5f * (xb[2] + p0[2]), &b2, &a2);
    __sincosf(0.5f * (xb[3] + p0[3]), &b3, &a3);
    __sincosf(0.5f * (xb[4] + p0[4]), &b4, &a4);
    __sincosf(0.5f * (xb[5] + p0[5]), &b5, &a5);
    __sincosf(0.5f * (xb[6] + p0[6]), &b6, &a6);
    __sincosf(0.5f * (xb[7] + p0[7]), &b7, &a7);
    __sincosf(0.5f * (xb[8] + p0[8]), &b8, &a8);
    __sincosf(0.5f * (xb[9] + p0[9]), &b9, &a9);
    __sincosf(0.5f * p0[10], &sz0, &cz0);
    __sincosf(0.5f * p0[11], &sz1, &cz1);
    __sincosf(0.5f * p0[12], &sz2, &cz2);
    __sincosf(0.5f * p0[13], &sz3, &cz3);
    __sincosf(0.5f * p0[14], &sz4, &cz4);
    __sincosf(0.5f * p0[15], &sz5, &cz5);
    __sincosf(0.5f * p0[16], &sz6, &cz6);
    __sincosf(0.5f * p0[17], &sz7, &cz7);
    __sincosf(0.5f * p0[18], &sz8, &cz8);
    __sincosf(0.5f * p0[19], &sz9, &cz9);

    float R = ((lane & 32) ? b0 : a0) * ((lane & 16) ? b1 : a1)
            * ((lane & 8)  ? b2 : a2) * ((lane & 4)  ? b3 : a3)
            * ((lane & 2)  ? b4 : a4) * ((lane & 1)  ? b5 : a5);
    float2 P = make_float2(cz0, (lane & 32) ? sz0 : -sz0);
    P = cmul(P, make_float2(cz1, (lane & 16) ? sz1 : -sz1));
    P = cmul(P, make_float2(cz2, (lane & 8)  ? sz2 : -sz2));
    P = cmul(P, make_float2(cz3, (lane & 4)  ? sz3 : -sz3));
    P = cmul(P, make_float2(cz4, (lane & 2)  ? sz4 : -sz4));
    P = cmul(P, make_float2(cz5, (lane & 1)  ? sz5 : -sz5));
    float2 laneC = make_float2(R * P.x, R * P.y);

    float2 u6w = wid ? make_float2(b6 * cz6,  b6 * sz6)
                     : make_float2(a6 * cz6, -a6 * sz6);
    float2 u7l = make_float2(a7 * cz7, -a7 * sz7), u7h = make_float2(b7 * cz7, b7 * sz7);
    float2 u8l = make_float2(a8 * cz8, -a8 * sz8), u8h = make_float2(b8 * cz8, b8 * sz8);
    float2 u9l = make_float2(a9 * cz9, -a9 * sz9), u9h = make_float2(b9 * cz9, b9 * sz9);

    float2 LW = cmul(laneC, u6w);
    // k = r>>1: bit1 = q7, bit0 = q8
    float2 LWA[4] = { cmul(LW, cmul(u7l, u8l)), cmul(LW, cmul(u7l, u8h)),
                      cmul(LW, cmul(u7h, u8l)), cmul(LW, cmul(u7h, u8h)) };
    float2 B2[2] = { u9l, u9h };

    float2 st[8];
#pragma unroll
    for (int r = 0; r < 8; ++r) st[r] = cmul(LWA[r >> 1], B2[r & 1]);

    // ---- ring (shared by layers 0..2) ----
    auto ring = [&]() {
        // CNOT(0,1)..(4,5): lane Gray permutation
        const int addr = ((lane ^ (lane >> 1)) & 63) << 2;
#pragma unroll
        for (int r = 0; r < 8; ++r) st[r] = bperm2(addr, st[r]);
        // CNOT(5,6): control lane mask1, target wave bit -> cross-wave select
        xw_write(st, buf, tid);
        __syncthreads();
        {
            float2 p[8];
            xw_read(p, buf, tid ^ 64);
            const bool sel = (lane & 1) != 0;
#pragma unroll
            for (int r = 0; r < 8; ++r) st[r] = sel ? p[r] : st[r];
        }
        __syncthreads();
        // CNOT(6,7): control wave bit, target reg bit4
        {
            const bool sel = wid != 0;
#pragma unroll
            for (int r = 0; r < 4; ++r) {
                float2 lo = st[r], hi = st[r + 4];
                st[r]     = sel ? hi : lo;
                st[r + 4] = sel ? lo : hi;
            }
        }
        // CNOT(7,8): control bit4, target bit2 (free renames)
        { float2 t = st[4]; st[4] = st[6]; st[6] = t; }
        { float2 t = st[5]; st[5] = st[7]; st[7] = t; }
        // CNOT(8,9): control bit2, target bit1
        { float2 t = st[2]; st[2] = st[3]; st[3] = t; }
        { float2 t = st[6]; st[6] = st[7]; st[7] = t; }
        // CNOT(9,0): control bit1, target lane mask32
        xch<32>(st[1].x, st[3].x); xch<32>(st[1].y, st[3].y);
        xch<32>(st[5].x, st[7].x); xch<32>(st[5].y, st[7].y);
    };

    ring();  // layer 0

    // ---- layers 1..3 ----
    float c, s;
#pragma unroll
    for (int l = 1; l < 4; ++l) {
        const float* pl = params + l * 2 * NQ;

        __sincosf(0.5f * pl[0], &s, &c); ry_lane_x<32>(st, lane, c, s);
        __sincosf(0.5f * pl[1], &s, &c); ry_lane_x<16>(st, lane, c, s);
        __sincosf(0.5f * pl[2], &s, &c); ry_lane<8>(st, lane, c, s);
        __sincosf(0.5f * pl[3], &s, &c); ry_lane<4>(st, lane, c, s);
        __sincosf(0.5f * pl[4], &s, &c); ry_lane<2>(st, lane, c, s);
        __sincosf(0.5f * pl[5], &s, &c); ry_lane<1>(st, lane, c, s);
        // q6: cross-wave RY (wave bit)
        {
            __sincosf(0.5f * pl[6], &s, &c);
            xw_write(st, buf, tid);
            __syncthreads();
            float2 p[8];
            xw_read(p, buf, tid ^ 64);
            const float cB = wid ? s : -s;
#pragma unroll
            for (int r = 0; r < 8; ++r) {
                st[r].x = c * st[r].x + cB * p[r].x;
                st[r].y = c * st[r].y + cB * p[r].y;
            }
            __syncthreads();
        }
        __sincosf(0.5f * pl[7], &s, &c); ry_reg<4>(st, c, s);
        __sincosf(0.5f * pl[8], &s, &c); ry_reg<2>(st, c, s);
        __sincosf(0.5f * pl[9], &s, &c); ry_reg<1>(st, c, s);

        if (l < 3) {
            // fused Z-diagonal
            float szq, czq;
            __sincosf(0.5f * pl[10], &szq, &czq);
            float2 PL = make_float2(czq, (lane & 32) ? szq : -szq);
            __sincosf(0.5f * pl[11], &szq, &czq);
            PL = cmul(PL, make_float2(czq, (lane & 16) ? szq : -szq));
            __sincosf(0.5f * pl[12], &szq, &czq);
            PL = cmul(PL, make_float2(czq, (lane & 8) ? szq : -szq));
            __sincosf(0.5f * pl[13], &szq, &czq);
            PL = cmul(PL, make_float2(czq, (lane & 4) ? szq : -szq));
            __sincosf(0.5f * pl[14], &szq, &czq);
            PL = cmul(PL, make_float2(czq, (lane & 2) ? szq : -szq));
            __sincosf(0.5f * pl[15], &szq, &czq);
            PL = cmul(PL, make_float2(czq, (lane & 1) ? szq : -szq));
            __sincosf(0.5f * pl[16], &szq, &czq);   // q6 on wave bit
            PL = cmul(PL, make_float2(czq, wid ? szq : -szq));
            float z7s, z7c, z8s, z8c, z9s, z9c;
            __sincosf(0.5f * pl[17], &z7s, &z7c);
            __sincosf(0.5f * pl[18], &z8s, &z8c);
            __sincosf(0.5f * pl[19], &z9s, &z9c);
            float2 PLA[4], zB[2];
#pragma unroll
            for (int k = 0; k < 4; ++k)
                PLA[k] = cmul(PL, cmul(make_float2(z7c, (k & 2) ? z7s : -z7s),
                                       make_float2(z8c, (k & 1) ? z8s : -z8s)));
            zB[0] = make_float2(z9c, -z9s);
            zB[1] = make_float2(z9c,  z9s);
#pragma unroll
            for (int r = 0; r < 8; ++r)
                st[r] = cmul(cmul(st[r], PLA[r >> 1]), zB[r & 1]);

            ring();
        }
    }

    // ---- readout (final ring folded into parity signs) ----
    // q0: lane31 & wave & reg7 ; q1..5: lane 48,56,60,62,63 ;
    // q6: lane63 & wave ; q7: +reg4 ; q8: +reg6 ; q9: +reg7.
    float S = 0.f, S4 = 0.f, S6 = 0.f, S7 = 0.f;
#pragma unroll
    for (int r = 0; r < 8; ++r) {
        float p = st[r].x * st[r].x + st[r].y * st[r].y;
        const int p2 = (r >> 2) & 1;
        const int p21 = p2 ^ ((r >> 1) & 1);
        const int p210 = p21 ^ (r & 1);
        S  += p;
        S4 += p2   ? -p : p;
        S6 += p21  ? -p : p;
        S7 += p210 ? -p : p;
    }
    const float ws = wid ? -1.f : 1.f;
    float A = S, Bv = ws * S, C = ws * S4, D = ws * S6, E = ws * S7;

    // cross-wave sum of the 5 accumulators
    {
        float* row = buf + tid * 16;
        row[0] = A; row[1] = Bv; row[2] = C; row[3] = D; row[4] = E;
        __syncthreads();
        const float* pr = buf + (tid ^ 64) * 16;
        A += pr[0]; Bv += pr[1]; C += pr[2]; D += pr[3]; E += pr[4];
    }

    if (wid == 0) {
        const float wA = wht64(A, lane);
        const float wB = wht64(Bv, lane);
        const float wC = wht64(C, lane);
        const float wD = wht64(D, lane);
        const float wE = wht64(E, lane);
        const long base = (long)b * NQ;
        if (lane == 31) out[base + 0] = wE;
        if (lane == 48) out[base + 1] = wA;
        if (lane == 56) out[base + 2] = wA;
        if (lane == 60) out[base + 3] = wA;
        if (lane == 62) out[base + 4] = wA;
        if (lane == 63) {
            out[base + 5] = wA;
            out[base + 6] = wB;
            out[base + 7] = wC;
            out[base + 8] = wD;
            out[base + 9] = wE;
        }
    }
}

extern "C" void kernel_launch(void* const* d_in, const int* in_sizes, int n_in,
                              void* d_out, int out_size, void* d_ws, size_t ws_size,
                              hipStream_t stream) {
    const float* x = (const float*)d_in[0];       // [B, 10]
    const float* params = (const float*)d_in[1];  // [4, 20]
    float* out = (float*)d_out;                   // [B, 10]
    const int B = in_sizes[0] / NQ;               // 4096
    pqc_kernel<<<B, 128, 0, stream>>>(x, params, out, B);  // 2 waves per sample
}

// Round 10
// 86.562 us; speedup vs baseline: 1.1219x; 1.1219x over previous
//
#include <hip/hip_runtime.h>

#define NQ 10

#if __has_builtin(__builtin_amdgcn_permlane16_swap)
#define HAVE_PLSWAP 1
#endif

// LDS exchange row stride in floats: 20 (80B). Bank of thread t's float4 k:
// (t*20 + 4k) % 32 — 8 consecutive threads cover all 32 banks exactly once
// -> conflict-free b128 exchange (R9's stride 16 hit {0,16} only: 1.85e7
// conflict cycles).
#define XSTR 20

// ---------- cross-lane helpers ----------
template<int M>
__device__ __forceinline__ float lx(float v) {
    if constexpr (M == 1)
        return __int_as_float(__builtin_amdgcn_mov_dpp(__float_as_int(v), 0xB1, 0xF, 0xF, true));
    else if constexpr (M == 2)
        return __int_as_float(__builtin_amdgcn_mov_dpp(__float_as_int(v), 0x4E, 0xF, 0xF, true));
    else if constexpr (M == 4) {
        int t = __builtin_amdgcn_mov_dpp(__float_as_int(v), 0x141, 0xF, 0xF, true); // xor7
        return __int_as_float(__builtin_amdgcn_mov_dpp(t, 0x1B, 0xF, 0xF, true));   // xor3
    } else if constexpr (M == 8)
        return __int_as_float(__builtin_amdgcn_mov_dpp(__float_as_int(v), 0x128, 0xF, 0xF, true));
    else if constexpr (M == 16)
        return __int_as_float(__builtin_amdgcn_ds_swizzle(__float_as_int(v), (16 << 10) | 0x1F));
    else
        return __shfl_xor(v, M, 64);
}

template<int M>
__device__ __forceinline__ float2 lx2(float2 v) {
    return make_float2(lx<M>(v.x), lx<M>(v.y));
}

// xch<M> (M=16,32): both values fetched from lane^M via DOUBLE permlane swap
// (direction-invariant; verified R6).
template<int M>
__device__ __forceinline__ void xch(float& a, float& b) {
#ifdef HAVE_PLSWAP
    if constexpr (M == 16) {
        auto r1 = __builtin_amdgcn_permlane16_swap(__float_as_uint(a), __float_as_uint(b), false, false);
        auto r2 = __builtin_amdgcn_permlane16_swap(r1[1], r1[0], false, false);
        a = __uint_as_float(r2[0]);
        b = __uint_as_float(r2[1]);
    } else {
        auto r1 = __builtin_amdgcn_permlane32_swap(__float_as_uint(a), __float_as_uint(b), false, false);
        auto r2 = __builtin_amdgcn_permlane32_swap(r1[1], r1[0], false, false);
        a = __uint_as_float(r2[0]);
        b = __uint_as_float(r2[1]);
    }
#else
    a = lx<M>(a);
    b = lx<M>(b);
#endif
}

__device__ __forceinline__ float2 cmul(float2 a, float2 b) {
    return make_float2(a.x * b.x - a.y * b.y, a.x * b.y + a.y * b.x);
}

__device__ __forceinline__ float2 bperm2(int addr, float2 v) {
    float2 r;
    r.x = __int_as_float(__builtin_amdgcn_ds_bpermute(addr, __float_as_int(v.x)));
    r.y = __int_as_float(__builtin_amdgcn_ds_bpermute(addr, __float_as_int(v.y)));
    return r;
}

// ---------- gates on an 8-reg half-state ----------
template<int M>
__device__ __forceinline__ void ry_lane(float2 st[8], int lane, float c, float s) {
    const float cB = (lane & M) ? s : -s;
#pragma unroll
    for (int r = 0; r < 8; ++r) {
        float2 part = lx2<M>(st[r]);
        st[r].x = c * st[r].x + cB * part.x;
        st[r].y = c * st[r].y + cB * part.y;
    }
}

template<int M>
__device__ __forceinline__ void ry_lane_x(float2 st[8], int lane, float c, float s) {
    const float cB = (lane & M) ? s : -s;
#pragma unroll
    for (int r = 0; r < 8; r += 2) {
        float pax = st[r].x, pay = st[r].y, pbx = st[r + 1].x, pby = st[r + 1].y;
        xch<M>(pax, pbx);
        xch<M>(pay, pby);
        st[r].x     = c * st[r].x     + cB * pax;
        st[r].y     = c * st[r].y     + cB * pay;
        st[r + 1].x = c * st[r + 1].x + cB * pbx;
        st[r + 1].y = c * st[r + 1].y + cB * pby;
    }
}

template<int RB>
__device__ __forceinline__ void ry_reg(float2 st[8], float c, float s) {
#pragma unroll
    for (int r = 0; r < 8; ++r) {
        if (r & RB) continue;
        float2 a0 = st[r], a1 = st[r | RB];
        st[r].x = c * a0.x - s * a1.x;
        st[r].y = c * a0.y - s * a1.y;
        st[r | RB].x = s * a0.x + c * a1.x;
        st[r | RB].y = s * a0.y + c * a1.y;
    }
}

// cross-wave exchange buffer helpers (stride XSTR floats per thread)
__device__ __forceinline__ void xw_write(const float2 st[8], float* buf, int tid) {
    float4* row = (float4*)(buf + tid * XSTR);
#pragma unroll
    for (int k = 0; k < 4; ++k)
        row[k] = make_float4(st[2 * k].x, st[2 * k].y, st[2 * k + 1].x, st[2 * k + 1].y);
}
__device__ __forceinline__ void xw_read(float2 p[8], const float* buf, int ptid) {
    const float4* row = (const float4*)(buf + ptid * XSTR);
#pragma unroll
    for (int k = 0; k < 4; ++k) {
        float4 v = row[k];
        p[2 * k]     = make_float2(v.x, v.y);
        p[2 * k + 1] = make_float2(v.z, v.w);
    }
}

__device__ __forceinline__ float wht64(float v, int lane) {
    float t;
    t = lx<1>(v);  v = (lane & 1)  ? (t - v) : (v + t);
    t = lx<2>(v);  v = (lane & 2)  ? (t - v) : (v + t);
    t = lx<4>(v);  v = (lane & 4)  ? (t - v) : (v + t);
    t = lx<8>(v);  v = (lane & 8)  ? (t - v) : (v + t);
    t = lx<16>(v); v = (lane & 16) ? (t - v) : (v + t);
    t = lx<32>(v); v = (lane & 32) ? (t - v) : (v + t);
    return v;
}

// ---------- main kernel: TWO waves per batch sample ----------
// State index s = (lane<<4) | (wid<<3) | r.
// Qubit q <-> state bit 9-q: q0..q5 -> lane masks 32..1, q6 -> wave bit,
// q7,q8,q9 -> reg bits 4,2,1.
__global__ __launch_bounds__(128, 8)
void pqc_kernel(const float* __restrict__ x,
                const float* __restrict__ params,
                float* __restrict__ out, int B) {
    const int tid  = threadIdx.x;
    const int lane = tid & 63;
    const int wid  = tid >> 6;
    const int b    = blockIdx.x;

    __shared__ float buf[128 * XSTR];   // 10 KB cross-wave exchange

    // ---- encoding + ENTIRE layer 0 (RY+RZ) folded into a product state ----
    const float* xb = x + (long)b * NQ;
    const float* p0 = params;
    float a0,b0,a1,b1,a2,b2,a3,b3,a4,b4,a5,b5,a6,b6,a7,b7,a8,b8,a9,b9;
    float cz0,sz0,cz1,sz1,cz2,sz2,cz3,sz3,cz4,sz4,cz5,sz5,cz6,sz6,cz7,sz7,cz8,sz8,cz9,sz9;
    __sincosf(0.5f * (xb[0] + p0[0]), &b0, &a0);
    __sincosf(0.5f * (xb[1] + p0[1]), &b1, &a1);
    __sincosf(0.5f * (xb[2] + p0[2]), &b2, &a2);
    __sincosf(0.5f * (xb[3] + p0[3]), &b3, &a3);
    __sincosf(0.5f * (xb[4] + p0[4]), &b4, &a4);
    __sincosf(0.5f * (xb[5] + p0[5]), &b5, &a5);
    __sincosf(0.5f * (xb[6] + p0[6]), &b6, &a6);
    __sincosf(0.5f * (xb[7] + p0[7]), &b7, &a7);
    __sincosf(0.5f * (xb[8] + p0[8]), &b8, &a8);
    __sincosf(0.5f * (xb[9] + p0[9]), &b9, &a9);
    __sincosf(0.5f * p0[10], &sz0, &cz0);
    __sincosf(0.5f * p0[11], &sz1, &cz1);
    __sincosf(0.5f * p0[12], &sz2, &cz2);
    __sincosf(0.5f * p0[13], &sz3, &cz3);
    __sincosf(0.5f * p0[14], &sz4, &cz4);
    __sincosf(0.5f * p0[15], &sz5, &cz5);
    __sincosf(0.5f * p0[16], &sz6, &cz6);
    __sincosf(0.5f * p0[17], &sz7, &cz7);
    __sincosf(0.5f * p0[18], &sz8, &cz8);
    __sincosf(0.5f * p0[19], &sz9, &cz9);

    float R = ((lane & 32) ? b0 : a0) * ((lane & 16) ? b1 : a1)
            * ((lane & 8)  ? b2 : a2) * ((lane & 4)  ? b3 : a3)
            * ((lane & 2)  ? b4 : a4) * ((lane & 1)  ? b5 : a5);
    float2 P = make_float2(cz0, (lane & 32) ? sz0 : -sz0);
    P = cmul(P, make_float2(cz1, (lane & 16) ? sz1 : -sz1));
    P = cmul(P, make_float2(cz2, (lane & 8)  ? sz2 : -sz2));
    P = cmul(P, make_float2(cz3, (lane & 4)  ? sz3 : -sz3));
    P = cmul(P, make_float2(cz4, (lane & 2)  ? sz4 : -sz4));
    P = cmul(P, make_float2(cz5, (lane & 1)  ? sz5 : -sz5));
    float2 laneC = make_float2(R * P.x, R * P.y);

    float2 u6w = wid ? make_float2(b6 * cz6,  b6 * sz6)
                     : make_float2(a6 * cz6, -a6 * sz6);
    float2 u7l = make_float2(a7 * cz7, -a7 * sz7), u7h = make_float2(b7 * cz7, b7 * sz7);
    float2 u8l = make_float2(a8 * cz8, -a8 * sz8), u8h = make_float2(b8 * cz8, b8 * sz8);
    float2 u9l = make_float2(a9 * cz9, -a9 * sz9), u9h = make_float2(b9 * cz9, b9 * sz9);

    float2 LW = cmul(laneC, u6w);
    // k = r>>1: bit1 = q7, bit0 = q8
    float2 LWA[4] = { cmul(LW, cmul(u7l, u8l)), cmul(LW, cmul(u7l, u8h)),
                      cmul(LW, cmul(u7h, u8l)), cmul(LW, cmul(u7h, u8h)) };
    float2 B2[2] = { u9l, u9h };

    float2 st[8];
#pragma unroll
    for (int r = 0; r < 8; ++r) st[r] = cmul(LWA[r >> 1], B2[r & 1]);

    // ---- ring (shared by layers 0..2) ----
    auto ring = [&]() {
        // CNOT(0,1)..(4,5): lane Gray permutation
        const int addr = ((lane ^ (lane >> 1)) & 63) << 2;
#pragma unroll
        for (int r = 0; r < 8; ++r) st[r] = bperm2(addr, st[r]);
        // CNOT(5,6): control lane mask1, target wave bit.
        // Only ODD lanes swap with the partner wave -> predicated exchange.
        if (lane & 1) xw_write(st, buf, tid);
        __syncthreads();
        if (lane & 1) {
            float2 p[8];
            xw_read(p, buf, tid ^ 64);
#pragma unroll
            for (int r = 0; r < 8; ++r) st[r] = p[r];
        }
        __syncthreads();
        // CNOT(6,7): control wave bit, target reg bit4
        {
            const bool sel = wid != 0;
#pragma unroll
            for (int r = 0; r < 4; ++r) {
                float2 lo = st[r], hi = st[r + 4];
                st[r]     = sel ? hi : lo;
                st[r + 4] = sel ? lo : hi;
            }
        }
        // CNOT(7,8): control bit4, target bit2 (free renames)
        { float2 t = st[4]; st[4] = st[6]; st[6] = t; }
        { float2 t = st[5]; st[5] = st[7]; st[7] = t; }
        // CNOT(8,9): control bit2, target bit1
        { float2 t = st[2]; st[2] = st[3]; st[3] = t; }
        { float2 t = st[6]; st[6] = st[7]; st[7] = t; }
        // CNOT(9,0): control bit1, target lane mask32
        xch<32>(st[1].x, st[3].x); xch<32>(st[1].y, st[3].y);
        xch<32>(st[5].x, st[7].x); xch<32>(st[5].y, st[7].y);
    };

    ring();  // layer 0

    // ---- layers 1..3 ----
    float c, s;
#pragma unroll
    for (int l = 1; l < 4; ++l) {
        const float* pl = params + l * 2 * NQ;

        __sincosf(0.5f * pl[0], &s, &c); ry_lane_x<32>(st, lane, c, s);
        __sincosf(0.5f * pl[1], &s, &c); ry_lane_x<16>(st, lane, c, s);
        __sincosf(0.5f * pl[2], &s, &c); ry_lane<8>(st, lane, c, s);
        __sincosf(0.5f * pl[3], &s, &c); ry_lane<4>(st, lane, c, s);
        __sincosf(0.5f * pl[4], &s, &c); ry_lane<2>(st, lane, c, s);
        __sincosf(0.5f * pl[5], &s, &c); ry_lane<1>(st, lane, c, s);
        // q6: cross-wave RY (wave bit)
        {
            __sincosf(0.5f * pl[6], &s, &c);
            xw_write(st, buf, tid);
            __syncthreads();
            float2 p[8];
            xw_read(p, buf, tid ^ 64);
            const float cB = wid ? s : -s;
#pragma unroll
            for (int r = 0; r < 8; ++r) {
                st[r].x = c * st[r].x + cB * p[r].x;
                st[r].y = c * st[r].y + cB * p[r].y;
            }
            __syncthreads();
        }
        __sincosf(0.5f * pl[7], &s, &c); ry_reg<4>(st, c, s);
        __sincosf(0.5f * pl[8], &s, &c); ry_reg<2>(st, c, s);
        __sincosf(0.5f * pl[9], &s, &c); ry_reg<1>(st, c, s);

        if (l < 3) {
            // fused Z-diagonal
            float szq, czq;
            __sincosf(0.5f * pl[10], &szq, &czq);
            float2 PL = make_float2(czq, (lane & 32) ? szq : -szq);
            __sincosf(0.5f * pl[11], &szq, &czq);
            PL = cmul(PL, make_float2(czq, (lane & 16) ? szq : -szq));
            __sincosf(0.5f * pl[12], &szq, &czq);
            PL = cmul(PL, make_float2(czq, (lane & 8) ? szq : -szq));
            __sincosf(0.5f * pl[13], &szq, &czq);
            PL = cmul(PL, make_float2(czq, (lane & 4) ? szq : -szq));
            __sincosf(0.5f * pl[14], &szq, &czq);
            PL = cmul(PL, make_float2(czq, (lane & 2) ? szq : -szq));
            __sincosf(0.5f * pl[15], &szq, &czq);
            PL = cmul(PL, make_float2(czq, (lane & 1) ? szq : -szq));
            __sincosf(0.5f * pl[16], &szq, &czq);   // q6 on wave bit
            PL = cmul(PL, make_float2(czq, wid ? szq : -szq));
            float z7s, z7c, z8s, z8c, z9s, z9c;
            __sincosf(0.5f * pl[17], &z7s, &z7c);
            __sincosf(0.5f * pl[18], &z8s, &z8c);
            __sincosf(0.5f * pl[19], &z9s, &z9c);
            float2 PLA[4], zB[2];
#pragma unroll
            for (int k = 0; k < 4; ++k)
                PLA[k] = cmul(PL, cmul(make_float2(z7c, (k & 2) ? z7s : -z7s),
                                       make_float2(z8c, (k & 1) ? z8s : -z8s)));
            zB[0] = make_float2(z9c, -z9s);
            zB[1] = make_float2(z9c,  z9s);
#pragma unroll
            for (int r = 0; r < 8; ++r)
                st[r] = cmul(cmul(st[r], PLA[r >> 1]), zB[r & 1]);

            ring();
        }
    }

    // ---- readout (final ring folded into parity signs) ----
    float S = 0.f, S4 = 0.f, S6 = 0.f, S7 = 0.f;
#pragma unroll
    for (int r = 0; r < 8; ++r) {
        float p = st[r].x * st[r].x + st[r].y * st[r].y;
        const int p2 = (r >> 2) & 1;
        const int p21 = p2 ^ ((r >> 1) & 1);
        const int p210 = p21 ^ (r & 1);
        S  += p;
        S4 += p2   ? -p : p;
        S6 += p21  ? -p : p;
        S7 += p210 ? -p : p;
    }
    const float wsgn = wid ? -1.f : 1.f;
    float A = S, Bv = wsgn * S, C = wsgn * S4, D = wsgn * S6, E = wsgn * S7;

    // cross-wave sum of the 5 accumulators
    {
        float* row = buf + tid * XSTR;
        row[0] = A; row[1] = Bv; row[2] = C; row[3] = D; row[4] = E;
        __syncthreads();
        const float* pr = buf + (tid ^ 64) * XSTR;
        A += pr[0]; Bv += pr[1]; C += pr[2]; D += pr[3]; E += pr[4];
    }

    if (wid == 0) {
        const float wA = wht64(A, lane);
        const float wB = wht64(Bv, lane);
        const float wC = wht64(C, lane);
        const float wD = wht64(D, lane);
        const float wE = wht64(E, lane);
        const long base = (long)b * NQ;
        if (lane == 31) out[base + 0] = wE;
        if (lane == 48) out[base + 1] = wA;
        if (lane == 56) out[base + 2] = wA;
        if (lane == 60) out[base + 3] = wA;
        if (lane == 62) out[base + 4] = wA;
        if (lane == 63) {
            out[base + 5] = wA;
            out[base + 6] = wB;
            out[base + 7] = wC;
            out[base + 8] = wD;
            out[base + 9] = wE;
        }
    }
}

extern "C" void kernel_launch(void* const* d_in, const int* in_sizes, int n_in,
                              void* d_out, int out_size, void* d_ws, size_t ws_size,
                              hipStream_t stream) {
    const float* x = (const float*)d_in[0];       // [B, 10]
    const float* params = (const float*)d_in[1];  // [4, 20]
    float* out = (float*)d_out;                   // [B, 10]
    const int B = in_sizes[0] / NQ;               // 4096
    pqc_kernel<<<B, 128, 0, stream>>>(x, params, out, B);  // 2 waves per sample
}

// Round 12
// 78.830 us; speedup vs baseline: 1.2320x; 1.0981x over previous
//
#include <hip/hip_runtime.h>

#define NQ 10

#if __has_builtin(__builtin_amdgcn_permlane16_swap)
#define HAVE_PLSWAP 1
#endif

typedef float v2f __attribute__((ext_vector_type(2)));

// ---------- cross-lane helpers ----------
// lx<M>: value from lane^M.
//   1,2 : DPP quad_perm                          (VALU)
//   4   : DPP half_mirror(xor7) + quad_perm xor3 (2x VALU)
//   8   : DPP row_ror:8                          (VALU)
//   16  : ds_swizzle (readout WHT only)
//   32  : __shfl_xor (readout WHT only)
template<int M>
__device__ __forceinline__ float lx(float v) {
    if constexpr (M == 1)
        return __int_as_float(__builtin_amdgcn_mov_dpp(__float_as_int(v), 0xB1, 0xF, 0xF, true));
    else if constexpr (M == 2)
        return __int_as_float(__builtin_amdgcn_mov_dpp(__float_as_int(v), 0x4E, 0xF, 0xF, true));
    else if constexpr (M == 4) {
        int t = __builtin_amdgcn_mov_dpp(__float_as_int(v), 0x141, 0xF, 0xF, true); // xor7
        return __int_as_float(__builtin_amdgcn_mov_dpp(t, 0x1B, 0xF, 0xF, true));   // xor3
    } else if constexpr (M == 8)
        return __int_as_float(__builtin_amdgcn_mov_dpp(__float_as_int(v), 0x128, 0xF, 0xF, true));
    else if constexpr (M == 16)
        return __int_as_float(__builtin_amdgcn_ds_swizzle(__float_as_int(v), (16 << 10) | 0x1F));
    else
        return __shfl_xor(v, M, 64);
}

template<int M>
__device__ __forceinline__ v2f lx2(v2f v) {
    v2f r;
    r.x = lx<M>(v.x);
    r.y = lx<M>(v.y);
    return r;
}

// xch<M> (M=16,32): both values fetched from lane^M via DOUBLE permlane swap
// (direction-invariant; verified R6).
template<int M>
__device__ __forceinline__ void xch(float& a, float& b) {
#ifdef HAVE_PLSWAP
    if constexpr (M == 16) {
        auto r1 = __builtin_amdgcn_permlane16_swap(__float_as_uint(a), __float_as_uint(b), false, false);
        auto r2 = __builtin_amdgcn_permlane16_swap(r1[1], r1[0], false, false);
        a = __uint_as_float(r2[0]);
        b = __uint_as_float(r2[1]);
    } else {
        auto r1 = __builtin_amdgcn_permlane32_swap(__float_as_uint(a), __float_as_uint(b), false, false);
        auto r2 = __builtin_amdgcn_permlane32_swap(r1[1], r1[0], false, false);
        a = __uint_as_float(r2[0]);
        b = __uint_as_float(r2[1]);
    }
#else
    a = lx<M>(a);
    b = lx<M>(b);
#endif
}

// vector-element-safe wrapper: ext_vector elements can't bind to float& —
// copy through locals (compiler elides the copies).
template<int M>
__device__ __forceinline__ void xch2(v2f& a, v2f& b) {
    float ax = a.x, bx = b.x, ay = a.y, by = b.y;
    xch<M>(ax, bx);
    xch<M>(ay, by);
    a.x = ax; a.y = ay; b.x = bx; b.y = by;
}

// complex multiply in packed form: (a.x,a.x)*b + (-a.y,a.y)*(b.y,b.x)
// -> v_pk_mul_f32 + v_pk_fma_f32 with swizzle/neg modifiers.
__device__ __forceinline__ v2f cmul(v2f a, v2f b) {
    v2f n; n.x = -a.y; n.y = a.y;
    return a.xx * b + n * b.yx;
}

__device__ __forceinline__ v2f bperm2(int addr, v2f v) {
    v2f r;
    r.x = __int_as_float(__builtin_amdgcn_ds_bpermute(addr, __float_as_int(v.x)));
    r.y = __int_as_float(__builtin_amdgcn_ds_bpermute(addr, __float_as_int(v.y)));
    return r;
}

// ---------- gates (16-reg full state, one wave per sample) ----------
template<int M>
__device__ __forceinline__ void ry_lane(v2f st[16], int lane, float c, float s) {
    const float cB = (lane & M) ? s : -s;
#pragma unroll
    for (int r = 0; r < 16; ++r) {
        v2f part = lx2<M>(st[r]);
        st[r] = c * st[r] + cB * part;     // v_pk_fma x1 per line pair
    }
}

template<int M>
__device__ __forceinline__ void ry_lane_x(v2f st[16], int lane, float c, float s) {
    const float cB = (lane & M) ? s : -s;
#pragma unroll
    for (int r = 0; r < 16; r += 2) {
        v2f pa = st[r], pb = st[r + 1];
        xch2<M>(pa, pb);
        st[r]     = c * st[r]     + cB * pa;
        st[r + 1] = c * st[r + 1] + cB * pb;
    }
}

template<int RB>
__device__ __forceinline__ void ry_reg(v2f st[16], float c, float s) {
#pragma unroll
    for (int r = 0; r < 16; ++r) {
        if (r & RB) continue;
        v2f a0 = st[r], a1 = st[r | RB];
        st[r]      = c * a0 - s * a1;
        st[r | RB] = s * a0 + c * a1;
    }
}

template<int MC, int RB>
__device__ __forceinline__ void cnot_lane_reg(v2f st[16], int lane) {
    const bool sel = (lane & MC) != 0;
#pragma unroll
    for (int r = 0; r < 16; ++r) {
        if (r & RB) continue;
        v2f lo = st[r], hi = st[r | RB];
        st[r]      = sel ? hi : lo;
        st[r | RB] = sel ? lo : hi;
    }
}

template<int RC, int RT>
__device__ __forceinline__ void cnot_reg_reg(v2f st[16]) {
#pragma unroll
    for (int r = 0; r < 16; ++r) {
        if ((r & RC) && !(r & RT)) {
            v2f t = st[r];
            st[r] = st[r | RT];
            st[r | RT] = t;
        }
    }
}

// CNOT(9,0): every ODD register gets xor-32; pair odd regs and use xch2<32>.
__device__ __forceinline__ void cnot_q9_q0(v2f st[16]) {
#pragma unroll
    for (int i = 0; i < 4; ++i) {
        const int ra = 4 * i + 1, rb = 4 * i + 3;
        xch2<32>(st[ra], st[rb]);
    }
}

__device__ __forceinline__ float wht64(float v, int lane) {
    float t;
    t = lx<1>(v);  v = (lane & 1)  ? (t - v) : (v + t);
    t = lx<2>(v);  v = (lane & 2)  ? (t - v) : (v + t);
    t = lx<4>(v);  v = (lane & 4)  ? (t - v) : (v + t);
    t = lx<8>(v);  v = (lane & 8)  ? (t - v) : (v + t);
    t = lx<16>(v); v = (lane & 16) ? (t - v) : (v + t);
    t = lx<32>(v); v = (lane & 32) ? (t - v) : (v + t);
    return v;
}

// ---------- main kernel: one wave per batch sample ----------
// State layout: s = lane*16 + r ; qubit q <-> state bit p = 9-q.
// Lane bits = state bits 9..4 (qubits 0..5), reg bits 3..0 (qubits 6..9).
__global__ __launch_bounds__(256)
void pqc_kernel(const float* __restrict__ x,
                const float* __restrict__ params,
                float* __restrict__ out, int B) {
    const int lane = threadIdx.x & 63;
    const int wave = threadIdx.x >> 6;
    const int b = blockIdx.x * 4 + wave;
    if (b >= B) return;

    // ---- encoding + ENTIRE layer 0 (RY+RZ) folded into a product state ----
    // RY(t)RY(x)|0> = RY(t+x)|0> = (cos h, sin h), h=(x+t)/2; then RZ phases:
    // u_q = (cos h * e^{-i hz}, sin h * e^{+i hz}).
    const float* xb = x + (long)b * NQ;
    const float* p0 = params;
    float a0,b0,a1,b1,a2,b2,a3,b3,a4,b4,a5,b5,a6,b6,a7,b7,a8,b8,a9,b9;
    float cz0,sz0,cz1,sz1,cz2,sz2,cz3,sz3,cz4,sz4,cz5,sz5,cz6,sz6,cz7,sz7,cz8,sz8,cz9,sz9;
    __sincosf(0.5f * (xb[0] + p0[0]), &b0, &a0);
    __sincosf(0.5f * (xb[1] + p0[1]), &b1, &a1);
    __sincosf(0.5f * (xb[2] + p0[2]), &b2, &a2);
    __sincosf(0.5f * (xb[3] + p0[3]), &b3, &a3);
    __sincosf(0.5f * (xb[4] + p0[4]), &b4, &a4);
    __sincosf(0.5f * (xb[5] + p0[5]), &b5, &a5);
    __sincosf(0.5f * (xb[6] + p0[6]), &b6, &a6);
    __sincosf(0.5f * (xb[7] + p0[7]), &b7, &a7);
    __sincosf(0.5f * (xb[8] + p0[8]), &b8, &a8);
    __sincosf(0.5f * (xb[9] + p0[9]), &b9, &a9);
    __sincosf(0.5f * p0[10], &sz0, &cz0);
    __sincosf(0.5f * p0[11], &sz1, &cz1);
    __sincosf(0.5f * p0[12], &sz2, &cz2);
    __sincosf(0.5f * p0[13], &sz3, &cz3);
    __sincosf(0.5f * p0[14], &sz4, &cz4);
    __sincosf(0.5f * p0[15], &sz5, &cz5);
    __sincosf(0.5f * p0[16], &sz6, &cz6);
    __sincosf(0.5f * p0[17], &sz7, &cz7);
    __sincosf(0.5f * p0[18], &sz8, &cz8);
    __sincosf(0.5f * p0[19], &sz9, &cz9);

    float R = ((lane & 32) ? b0 : a0) * ((lane & 16) ? b1 : a1)
            * ((lane & 8)  ? b2 : a2) * ((lane & 4)  ? b3 : a3)
            * ((lane & 2)  ? b4 : a4) * ((lane & 1)  ? b5 : a5);
    v2f P; P.x = cz0; P.y = (lane & 32) ? sz0 : -sz0;
    { v2f t; t.x = cz1; t.y = (lane & 16) ? sz1 : -sz1; P = cmul(P, t); }
    { v2f t; t.x = cz2; t.y = (lane & 8)  ? sz2 : -sz2; P = cmul(P, t); }
    { v2f t; t.x = cz3; t.y = (lane & 4)  ? sz3 : -sz3; P = cmul(P, t); }
    { v2f t; t.x = cz4; t.y = (lane & 2)  ? sz4 : -sz4; P = cmul(P, t); }
    { v2f t; t.x = cz5; t.y = (lane & 1)  ? sz5 : -sz5; P = cmul(P, t); }
    v2f laneC = R * P;

    v2f u6l = { a6 * cz6, -a6 * sz6 }, u6h = { b6 * cz6, b6 * sz6 };
    v2f u7l = { a7 * cz7, -a7 * sz7 }, u7h = { b7 * cz7, b7 * sz7 };
    v2f u8l = { a8 * cz8, -a8 * sz8 }, u8h = { b8 * cz8, b8 * sz8 };
    v2f u9l = { a9 * cz9, -a9 * sz9 }, u9h = { b9 * cz9, b9 * sz9 };
    v2f A2[4] = { cmul(u6l, u7l), cmul(u6l, u7h), cmul(u6h, u7l), cmul(u6h, u7h) };
    v2f B2[4] = { cmul(u8l, u9l), cmul(u8l, u9h), cmul(u8h, u9l), cmul(u8h, u9h) };
    v2f LA[4] = { cmul(laneC, A2[0]), cmul(laneC, A2[1]),
                  cmul(laneC, A2[2]), cmul(laneC, A2[3]) };

    v2f st[16];
#pragma unroll
    for (int r = 0; r < 16; ++r) st[r] = cmul(LA[r >> 2], B2[r & 3]);

    // ---- layer 0 CNOT ring ----
    {
        const int addr = ((lane ^ (lane >> 1)) & 63) << 2;
#pragma unroll
        for (int r = 0; r < 16; ++r) st[r] = bperm2(addr, st[r]);
        cnot_lane_reg<1, 8>(st, lane);
        cnot_reg_reg<8, 4>(st);
        cnot_reg_reg<4, 2>(st);
        cnot_reg_reg<2, 1>(st);
        cnot_q9_q0(st);
    }

    // ---- layers 1..3 (complex); last layer's diagonal+ring folded away ----
    float c, s;
#pragma unroll
    for (int l = 1; l < 4; ++l) {
        const float* pl = params + l * 2 * NQ;

        __sincosf(0.5f * pl[0], &s, &c); ry_lane_x<32>(st, lane, c, s);
        __sincosf(0.5f * pl[1], &s, &c); ry_lane_x<16>(st, lane, c, s);
        __sincosf(0.5f * pl[2], &s, &c); ry_lane<8>(st, lane, c, s);
        __sincosf(0.5f * pl[3], &s, &c); ry_lane<4>(st, lane, c, s);
        __sincosf(0.5f * pl[4], &s, &c); ry_lane<2>(st, lane, c, s);
        __sincosf(0.5f * pl[5], &s, &c); ry_lane<1>(st, lane, c, s);
        __sincosf(0.5f * pl[6], &s, &c); ry_reg<8>(st, c, s);
        __sincosf(0.5f * pl[7], &s, &c); ry_reg<4>(st, c, s);
        __sincosf(0.5f * pl[8], &s, &c); ry_reg<2>(st, c, s);
        __sincosf(0.5f * pl[9], &s, &c); ry_reg<1>(st, c, s);

        if (l < 3) {
            float sz, cz;
            __sincosf(0.5f * pl[10], &sz, &cz);
            v2f PL; PL.x = cz; PL.y = (lane & 32) ? sz : -sz;
            __sincosf(0.5f * pl[11], &sz, &cz);
            { v2f t; t.x = cz; t.y = (lane & 16) ? sz : -sz; PL = cmul(PL, t); }
            __sincosf(0.5f * pl[12], &sz, &cz);
            { v2f t; t.x = cz; t.y = (lane & 8)  ? sz : -sz; PL = cmul(PL, t); }
            __sincosf(0.5f * pl[13], &sz, &cz);
            { v2f t; t.x = cz; t.y = (lane & 4)  ? sz : -sz; PL = cmul(PL, t); }
            __sincosf(0.5f * pl[14], &sz, &cz);
            { v2f t; t.x = cz; t.y = (lane & 2)  ? sz : -sz; PL = cmul(PL, t); }
            __sincosf(0.5f * pl[15], &sz, &cz);
            { v2f t; t.x = cz; t.y = (lane & 1)  ? sz : -sz; PL = cmul(PL, t); }

            float z6s, z6c, z7s, z7c, z8s, z8c, z9s, z9c;
            __sincosf(0.5f * pl[16], &z6s, &z6c);
            __sincosf(0.5f * pl[17], &z7s, &z7c);
            __sincosf(0.5f * pl[18], &z8s, &z8c);
            __sincosf(0.5f * pl[19], &z9s, &z9c);
            v2f A[4], Bb[4];
#pragma unroll
            for (int k = 0; k < 4; ++k) {
                v2f t6; t6.x = z6c; t6.y = (k & 2) ? z6s : -z6s;
                v2f t7; t7.x = z7c; t7.y = (k & 1) ? z7s : -z7s;
                A[k] = cmul(cmul(t6, t7), PL);
                v2f t8; t8.x = z8c; t8.y = (k & 2) ? z8s : -z8s;
                v2f t9; t9.x = z9c; t9.y = (k & 1) ? z9s : -z9s;
                Bb[k] = cmul(t8, t9);
            }
#pragma unroll
            for (int r = 0; r < 16; ++r)
                st[r] = cmul(cmul(st[r], A[r >> 2]), Bb[r & 3]);

            const int addr = ((lane ^ (lane >> 1)) & 63) << 2;
#pragma unroll
            for (int r = 0; r < 16; ++r) st[r] = bperm2(addr, st[r]);
            cnot_lane_reg<1, 8>(st, lane);
            cnot_reg_reg<8, 4>(st);
            cnot_reg_reg<4, 2>(st);
            cnot_reg_reg<2, 1>(st);
            cnot_q9_q0(st);
        }
    }

    // ---- readout (final ring folded into parity signs) ----
    float lane_sum = 0.f, A3 = 0.f, A32 = 0.f, A321 = 0.f, A3210 = 0.f;
#pragma unroll
    for (int r = 0; r < 16; ++r) {
        float p = st[r].x * st[r].x + st[r].y * st[r].y;
        const int p3 = (r >> 3) & 1;
        const int p32 = p3 ^ ((r >> 2) & 1);
        const int p321 = p32 ^ ((r >> 1) & 1);
        const int p3210 = p321 ^ (r & 1);
        lane_sum += p;
        A3    += p3    ? -p : p;
        A32   += p32   ? -p : p;
        A321  += p321  ? -p : p;
        A3210 += p3210 ? -p : p;
    }
    const float wLS   = wht64(lane_sum, lane);
    const float w3    = wht64(A3, lane);
    const float w32   = wht64(A32, lane);
    const float w321  = wht64(A321, lane);
    const float w3210 = wht64(A3210, lane);

    const long base = (long)b * NQ;
    if (lane == 31) out[base + 0] = w3210;
    if (lane == 48) out[base + 1] = wLS;
    if (lane == 56) out[base + 2] = wLS;
    if (lane == 60) out[base + 3] = wLS;
    if (lane == 62) out[base + 4] = wLS;
    if (lane == 63) {
        out[base + 5] = wLS;
        out[base + 6] = w3;
        out[base + 7] = w32;
        out[base + 8] = w321;
        out[base + 9] = w3210;
    }
}

extern "C" void kernel_launch(void* const* d_in, const int* in_sizes, int n_in,
                              void* d_out, int out_size, void* d_ws, size_t ws_size,
                              hipStream_t stream) {
    const float* x = (const float*)d_in[0];       // [B, 10]
    const float* params = (const float*)d_in[1];  // [4, 20]
    float* out = (float*)d_out;                   // [B, 10]
    const int B = in_sizes[0] / NQ;               // 4096
    const int grid = (B + 3) / 4;                 // 4 waves (samples) per block
    pqc_kernel<<<grid, 256, 0, stream>>>(x, params, out, B);
}

// Round 14
// 77.847 us; speedup vs baseline: 1.2475x; 1.0126x over previous
//
#include <hip/hip_runtime.h>

#define NQ 10

typedef float v2f __attribute__((ext_vector_type(2)));

// ================= compile-time GF(2) ring-frame machinery =================
// Ring = CNOT(0,1)CNOT(1,2)...CNOT(9,0) maps basis label bits linearly:
// new qk = q0^..^qk (k>=1), new q0 = q1^..^q9. Stored state phi[t] = psi[F t];
// after l virtual rings F = R^l. A true RY on qubit q acts on stored pairs
// (t, t^m) with m = F^-1 e_q and role bit = <row_q(F), t>.
struct M10 { unsigned r[10]; };

constexpr M10 mk_R() {
    M10 A{};
    A.r[0] = 0b1111111110u;                       // q1..q9
    for (int k = 1; k < 10; ++k) A.r[k] = (1u << (k + 1)) - 1u;  // q0..qk
    return A;
}
constexpr M10 mk_Rinv() {
    M10 A{};
    A.r[0] = (1u << 0) | (1u << 9);
    A.r[1] = (1u << 0) | (1u << 1) | (1u << 9);
    for (int k = 2; k < 10; ++k) A.r[k] = (1u << (k - 1)) | (1u << k);
    return A;
}
constexpr M10 mmul(M10 A, M10 B) {   // row_k(AB) = xor of B-rows j where A[k] has bit j
    M10 C{};
    for (int k = 0; k < 10; ++k) {
        unsigned v = 0;
        for (int j = 0; j < 10; ++j)
            if ((A.r[k] >> j) & 1u) v ^= B.r[j];
        C.r[k] = v;
    }
    return C;
}
constexpr M10 RF  = mk_R();
constexpr M10 RV  = mk_Rinv();
constexpr M10 RF2 = mmul(RF, RF);
constexpr M10 RF3 = mmul(RF2, RF);
constexpr M10 RF4 = mmul(RF2, RF2);
constexpr M10 RV2 = mmul(RV, RV);
constexpr M10 RV3 = mmul(RV2, RV);

constexpr bool isI(M10 A) {
    for (int k = 0; k < 10; ++k) if (A.r[k] != (1u << k)) return false;
    return true;
}
static_assert(isI(mmul(RF, RV)), "Rinv wrong");
static_assert(isI(mmul(RV3, RF3)), "powers wrong");

constexpr unsigned colq(M10 A, int q) {           // column q as qubit-mask
    unsigned m = 0;
    for (int k = 0; k < 10; ++k) m |= ((A.r[k] >> q) & 1u) << k;
    return m;
}
// qubit-mask -> lane mask (qubits 0..5 -> lane bits 32..1) / reg mask (6..9 -> 8..1)
constexpr int laneM(unsigned qm) {
    int m = 0;
    for (int q = 0; q <= 5; ++q) if ((qm >> q) & 1u) m |= 1 << (5 - q);
    return m;
}
constexpr int regM(unsigned qm) {
    int m = 0;
    for (int q = 6; q <= 9; ++q) if ((qm >> q) & 1u) m |= 1 << (9 - q);
    return m;
}

// ================= cross-lane exchange: value from lane^M =================
template<int CTRL>
__device__ __forceinline__ float dppmov(float v) {
    return __int_as_float(__builtin_amdgcn_mov_dpp(__float_as_int(v), CTRL, 0xF, 0xF, true));
}
template<int M>
__device__ __forceinline__ float lx(float v) {
    static_assert(M > 0 && M < 64, "mask");
    if constexpr (M == 1)       return dppmov<0xB1>(v);   // quad_perm xor1
    else if constexpr (M == 2)  return dppmov<0x4E>(v);   // xor2
    else if constexpr (M == 3)  return dppmov<0x1B>(v);   // xor3
    else if constexpr (M == 7)  return dppmov<0x141>(v);  // row_half_mirror = xor7
    else if constexpr (M == 8)  return dppmov<0x128>(v);  // row_ror:8 = xor8
    else if constexpr (M == 15) return dppmov<0x140>(v);  // row_mirror = xor15
    else if constexpr (M == 4)  return lx<3>(lx<7>(v));
    else if constexpr (M == 5)  return lx<2>(lx<7>(v));
    else if constexpr (M == 6)  return lx<1>(lx<7>(v));
    else if constexpr (M == 9)  return lx<1>(lx<8>(v));
    else if constexpr (M == 10) return lx<2>(lx<8>(v));
    else if constexpr (M == 11) return lx<3>(lx<8>(v));
    else if constexpr (M == 12) return lx<3>(lx<15>(v));
    else if constexpr (M == 13) return lx<2>(lx<15>(v));
    else if constexpr (M == 14) return lx<1>(lx<15>(v));
    else if constexpr (M < 32)
        return __int_as_float(__builtin_amdgcn_ds_swizzle(__float_as_int(v), (M << 10) | 0x1F));
    else
        return __shfl_xor(v, M, 64);
}

__device__ __forceinline__ v2f cmul(v2f a, v2f b) {   // packed complex mul
    v2f n; n.x = -a.y; n.y = a.y;
    return a.xx * b + n * b.yx;
}

// ============ generalized RY: flip mask (LM,RM), role (LW,RW) ============
// new = c*me + cB*partner, cB = role ? s : -s, role = par(lane&LW)^par(r&RW)
template<int LM, int RM, int LW, int RW>
__device__ __forceinline__ void ry_g(v2f st[16], int lane, float c, float s) {
    static_assert((LM | RM) != 0, "null mask");
    const float baseP = (__builtin_popcount((unsigned)(lane & LW)) & 1) ? s : -s;
    if constexpr (RM == 0) {
#pragma unroll
        for (int r = 0; r < 16; ++r) {
            v2f part;
            part.x = lx<LM ? LM : 1>(st[r].x);
            part.y = lx<LM ? LM : 1>(st[r].y);
            const float cB = (__builtin_popcount((unsigned)(r & RW)) & 1) ? -baseP : baseP;
            st[r] = c * st[r] + cB * part;
        }
    } else {
        constexpr int PIV = RM & (-RM);
#pragma unroll
        for (int r = 0; r < 16; ++r) {
            if (r & PIV) continue;
            const int rb = r ^ RM;
            v2f ea, eb;
            if constexpr (LM != 0) {
                ea.x = lx<LM ? LM : 1>(st[r].x);  ea.y = lx<LM ? LM : 1>(st[r].y);
                eb.x = lx<LM ? LM : 1>(st[rb].x); eb.y = lx<LM ? LM : 1>(st[rb].y);
            } else {
                ea = st[r]; eb = st[rb];
            }
            const float cBa = (__builtin_popcount((unsigned)(r & RW)) & 1) ? -baseP : baseP;
            const float cBb = (__builtin_popcount((unsigned)(rb & RW)) & 1) ? -baseP : baseP;
            st[r]  = c * st[r]  + cBa * eb;
            st[rb] = c * st[rb] + cBb * ea;
        }
    }
}

// ============ generalized fused Z-diagonal at frame R^L ============
// phase angle phi(t) = sum_q hz_q * (role_q ? +1 : -1); role = par(lane&LW)^par(r&RW)
// = per-reg-bin angle via 16-bin WHT of lane-signed angle sums.
template<int L>
__device__ __forceinline__ void diag_g(v2f st[16], int lane, const float* pl) {
    constexpr M10 W = (L == 1) ? RF : RF2;
    float G[16];
#pragma unroll
    for (int i = 0; i < 16; ++i) G[i] = 0.f;
#pragma unroll
    for (int q = 0; q < 10; ++q) {
        const int LWq = laneM(W.r[q]);
        const int RWq = regM(W.r[q]);
        const float hz = 0.5f * pl[10 + q];
        const float gq = (__builtin_popcount((unsigned)(lane & LWq)) & 1) ? hz : -hz;
        G[RWq] += gq;
    }
#pragma unroll
    for (int m = 1; m < 16; m <<= 1) {
#pragma unroll
        for (int r = 0; r < 16; ++r) {
            if (r & m) continue;
            const float a = G[r], bb = G[r | m];
            G[r] = a + bb;
            G[r | m] = a - bb;
        }
    }
#pragma unroll
    for (int r = 0; r < 16; ++r) {
        float sn, cs;
        __sincosf(G[r], &sn, &cs);
        v2f d; d.x = cs; d.y = sn;
        st[r] = cmul(st[r], d);
    }
}

__device__ __forceinline__ float wht64(float v, int lane) {
    float t;
    t = lx<1>(v);  v = (lane & 1)  ? (t - v) : (v + t);
    t = lx<2>(v);  v = (lane & 2)  ? (t - v) : (v + t);
    t = lx<4>(v);  v = (lane & 4)  ? (t - v) : (v + t);
    t = lx<8>(v);  v = (lane & 8)  ? (t - v) : (v + t);
    t = lx<16>(v); v = (lane & 16) ? (t - v) : (v + t);
    t = lx<32>(v); v = (lane & 32) ? (t - v) : (v + t);
    return v;
}

// ================= main kernel: one wave per batch sample =================
// Stored label t: lane bits = qubits 0..5 (masks 32..1), reg bits = qubits
// 6..9 (masks 8..1). Rings are NEVER applied — frame-tracked via R^l.
__global__ __launch_bounds__(256)
void pqc_kernel(const float* __restrict__ x,
                const float* __restrict__ params,
                float* __restrict__ out, int B) {
    const int lane = threadIdx.x & 63;
    const int wave = threadIdx.x >> 6;
    const int b = blockIdx.x * 4 + wave;
    if (b >= B) return;

    // ---- encoding + ENTIRE layer 0 (RY+RZ) folded into a product state ----
    const float* xb = x + (long)b * NQ;
    const float* p0 = params;
    float a0,b0,a1,b1,a2,b2,a3,b3,a4,b4,a5,b5,a6,b6,a7,b7,a8,b8,a9,b9;
    float cz0,sz0,cz1,sz1,cz2,sz2,cz3,sz3,cz4,sz4,cz5,sz5,cz6,sz6,cz7,sz7,cz8,sz8,cz9,sz9;
    __sincosf(0.5f * (xb[0] + p0[0]), &b0, &a0);
    __sincosf(0.5f * (xb[1] + p0[1]), &b1, &a1);
    __sincosf(0.5f * (xb[2] + p0[2]), &b2, &a2);
    __sincosf(0.5f * (xb[3] + p0[3]), &b3, &a3);
    __sincosf(0.5f * (xb[4] + p0[4]), &b4, &a4);
    __sincosf(0.5f * (xb[5] + p0[5]), &b5, &a5);
    __sincosf(0.5f * (xb[6] + p0[6]), &b6, &a6);
    __sincosf(0.5f * (xb[7] + p0[7]), &b7, &a7);
    __sincosf(0.5f * (xb[8] + p0[8]), &b8, &a8);
    __sincosf(0.5f * (xb[9] + p0[9]), &b9, &a9);
    __sincosf(0.5f * p0[10], &sz0, &cz0);
    __sincosf(0.5f * p0[11], &sz1, &cz1);
    __sincosf(0.5f * p0[12], &sz2, &cz2);
    __sincosf(0.5f * p0[13], &sz3, &cz3);
    __sincosf(0.5f * p0[14], &sz4, &cz4);
    __sincosf(0.5f * p0[15], &sz5, &cz5);
    __sincosf(0.5f * p0[16], &sz6, &cz6);
    __sincosf(0.5f * p0[17], &sz7, &cz7);
    __sincosf(0.5f * p0[18], &sz8, &cz8);
    __sincosf(0.5f * p0[19], &sz9, &cz9);

    float R = ((lane & 32) ? b0 : a0) * ((lane & 16) ? b1 : a1)
            * ((lane & 8)  ? b2 : a2) * ((lane & 4)  ? b3 : a3)
            * ((lane & 2)  ? b4 : a4) * ((lane & 1)  ? b5 : a5);
    v2f P; P.x = cz0; P.y = (lane & 32) ? sz0 : -sz0;
    { v2f t; t.x = cz1; t.y = (lane & 16) ? sz1 : -sz1; P = cmul(P, t); }
    { v2f t; t.x = cz2; t.y = (lane & 8)  ? sz2 : -sz2; P = cmul(P, t); }
    { v2f t; t.x = cz3; t.y = (lane & 4)  ? sz3 : -sz3; P = cmul(P, t); }
    { v2f t; t.x = cz4; t.y = (lane & 2)  ? sz4 : -sz4; P = cmul(P, t); }
    { v2f t; t.x = cz5; t.y = (lane & 1)  ? sz5 : -sz5; P = cmul(P, t); }
    v2f laneC = R * P;

    v2f u6l = { a6 * cz6, -a6 * sz6 }, u6h = { b6 * cz6, b6 * sz6 };
    v2f u7l = { a7 * cz7, -a7 * sz7 }, u7h = { b7 * cz7, b7 * sz7 };
    v2f u8l = { a8 * cz8, -a8 * sz8 }, u8h = { b8 * cz8, b8 * sz8 };
    v2f u9l = { a9 * cz9, -a9 * sz9 }, u9h = { b9 * cz9, b9 * sz9 };
    v2f A2[4] = { cmul(u6l, u7l), cmul(u6l, u7h), cmul(u6h, u7l), cmul(u6h, u7h) };
    v2f B2[4] = { cmul(u8l, u9l), cmul(u8l, u9h), cmul(u8h, u9l), cmul(u8h, u9h) };
    v2f LA[4] = { cmul(laneC, A2[0]), cmul(laneC, A2[1]),
                  cmul(laneC, A2[2]), cmul(laneC, A2[3]) };

    v2f st[16];
#pragma unroll
    for (int r = 0; r < 16; ++r) st[r] = cmul(LA[r >> 2], B2[r & 3]);
    // (layer-0 ring is virtual: F = R from here on)

#define GATE(INV, ROLE, Q, ANG) do { \
    float gc_, gs_; __sincosf(0.5f * (ANG), &gs_, &gc_); \
    ry_g<laneM(colq(INV, Q)), regM(colq(INV, Q)), \
         laneM(ROLE.r[Q]), regM(ROLE.r[Q])>(st, lane, gc_, gs_); \
} while (0)

    // ---- layer 1 (frame F = R) ----
    {
        const float* pl = params + 20;
        GATE(RV, RF, 0, pl[0]); GATE(RV, RF, 1, pl[1]);
        GATE(RV, RF, 2, pl[2]); GATE(RV, RF, 3, pl[3]);
        GATE(RV, RF, 4, pl[4]); GATE(RV, RF, 5, pl[5]);
        GATE(RV, RF, 6, pl[6]); GATE(RV, RF, 7, pl[7]);
        GATE(RV, RF, 8, pl[8]); GATE(RV, RF, 9, pl[9]);
        diag_g<1>(st, lane, pl);
    }
    // ---- layer 2 (frame F = R^2) ----
    {
        const float* pl = params + 40;
        GATE(RV2, RF2, 0, pl[0]); GATE(RV2, RF2, 1, pl[1]);
        GATE(RV2, RF2, 2, pl[2]); GATE(RV2, RF2, 3, pl[3]);
        GATE(RV2, RF2, 4, pl[4]); GATE(RV2, RF2, 5, pl[5]);
        GATE(RV2, RF2, 6, pl[6]); GATE(RV2, RF2, 7, pl[7]);
        GATE(RV2, RF2, 8, pl[8]); GATE(RV2, RF2, 9, pl[9]);
        diag_g<2>(st, lane, pl);
    }
    // ---- layer 3 (frame F = R^3; diag+final ring fold into readout) ----
    {
        const float* pl = params + 60;
        GATE(RV3, RF3, 0, pl[0]); GATE(RV3, RF3, 1, pl[1]);
        GATE(RV3, RF3, 2, pl[2]); GATE(RV3, RF3, 3, pl[3]);
        GATE(RV3, RF3, 4, pl[4]); GATE(RV3, RF3, 5, pl[5]);
        GATE(RV3, RF3, 6, pl[6]); GATE(RV3, RF3, 7, pl[7]);
        GATE(RV3, RF3, 8, pl[8]); GATE(RV3, RF3, 9, pl[9]);
    }
#undef GATE

    // ---- readout: <Z_q> with roles = rows of R^4 ----
    float p[16];
#pragma unroll
    for (int r = 0; r < 16; ++r)
        p[r] = st[r].x * st[r].x + st[r].y * st[r].y;
#pragma unroll
    for (int m = 1; m < 16; m <<= 1) {
#pragma unroll
        for (int r = 0; r < 16; ++r) {
            if (r & m) continue;
            const float a = p[r], bb = p[r | m];
            p[r] = a + bb;
            p[r | m] = a - bb;
        }
    }
    const long base = (long)b * NQ;
#pragma unroll
    for (int q = 0; q < 10; ++q) {
        const int LWq = laneM(RF4.r[q]);
        const int RWq = regM(RF4.r[q]);
        const float v = wht64(p[RWq], lane);
        if (lane == LWq) out[base + q] = v;
    }
}

extern "C" void kernel_launch(void* const* d_in, const int* in_sizes, int n_in,
                              void* d_out, int out_size, void* d_ws, size_t ws_size,
                              hipStream_t stream) {
    const float* x = (const float*)d_in[0];       // [B, 10]
    const float* params = (const float*)d_in[1];  // [4, 20]
    float* out = (float*)d_out;                   // [B, 10]
    const int B = in_sizes[0] / NQ;               // 4096
    const int grid = (B + 3) / 4;                 // 4 waves (samples) per block
    pqc_kernel<<<grid, 256, 0, stream>>>(x, params, out, B);
}

// Round 15
// 77.577 us; speedup vs baseline: 1.2519x; 1.0035x over previous
//
#include <hip/hip_runtime.h>

#define NQ 10

typedef float v2f __attribute__((ext_vector_type(2)));

// ================= compile-time GF(2) ring-frame machinery =================
// Ring = CNOT(0,1)...CNOT(9,0) is linear on basis labels. Stored state
// phi[t] = psi[F t], F = R^l. True RY on qubit q acts on stored pairs
// (t, t^m), m = F^-1 e_q, role bit = <row_q(F), t>.
struct M10 { unsigned r[10]; };

constexpr M10 mk_R() {
    M10 A{};
    A.r[0] = 0b1111111110u;
    for (int k = 1; k < 10; ++k) A.r[k] = (1u << (k + 1)) - 1u;
    return A;
}
constexpr M10 mk_Rinv() {
    M10 A{};
    A.r[0] = (1u << 0) | (1u << 9);
    A.r[1] = (1u << 0) | (1u << 1) | (1u << 9);
    for (int k = 2; k < 10; ++k) A.r[k] = (1u << (k - 1)) | (1u << k);
    return A;
}
constexpr M10 mmul(M10 A, M10 B) {
    M10 C{};
    for (int k = 0; k < 10; ++k) {
        unsigned v = 0;
        for (int j = 0; j < 10; ++j)
            if ((A.r[k] >> j) & 1u) v ^= B.r[j];
        C.r[k] = v;
    }
    return C;
}
constexpr M10 RF  = mk_R();
constexpr M10 RV  = mk_Rinv();
constexpr M10 RF2 = mmul(RF, RF);
constexpr M10 RF3 = mmul(RF2, RF);
constexpr M10 RF4 = mmul(RF2, RF2);
constexpr M10 RV2 = mmul(RV, RV);
constexpr M10 RV3 = mmul(RV2, RV);

constexpr bool isI(M10 A) {
    for (int k = 0; k < 10; ++k) if (A.r[k] != (1u << k)) return false;
    return true;
}
static_assert(isI(mmul(RF, RV)), "Rinv wrong");
static_assert(isI(mmul(RV3, RF3)), "powers wrong");

constexpr unsigned colq(M10 A, int q) {
    unsigned m = 0;
    for (int k = 0; k < 10; ++k) m |= ((A.r[k] >> q) & 1u) << k;
    return m;
}
constexpr int laneM(unsigned qm) {
    int m = 0;
    for (int q = 0; q <= 5; ++q) if ((qm >> q) & 1u) m |= 1 << (5 - q);
    return m;
}
constexpr int regM(unsigned qm) {
    int m = 0;
    for (int q = 6; q <= 9; ++q) if ((qm >> q) & 1u) m |= 1 << (9 - q);
    return m;
}

// ================= cross-lane exchange: value from lane^M =================
template<int CTRL>
__device__ __forceinline__ float dppmov(float v) {
    return __int_as_float(__builtin_amdgcn_mov_dpp(__float_as_int(v), CTRL, 0xF, 0xF, true));
}
template<int M>
__device__ __forceinline__ float lx(float v) {
    static_assert(M > 0 && M < 64, "mask");
    if constexpr (M == 1)       return dppmov<0xB1>(v);
    else if constexpr (M == 2)  return dppmov<0x4E>(v);
    else if constexpr (M == 3)  return dppmov<0x1B>(v);
    else if constexpr (M == 7)  return dppmov<0x141>(v);
    else if constexpr (M == 8)  return dppmov<0x128>(v);
    else if constexpr (M == 15) return dppmov<0x140>(v);
    else if constexpr (M == 4)  return lx<3>(lx<7>(v));
    else if constexpr (M == 5)  return lx<2>(lx<7>(v));
    else if constexpr (M == 6)  return lx<1>(lx<7>(v));
    else if constexpr (M == 9)  return lx<1>(lx<8>(v));
    else if constexpr (M == 10) return lx<2>(lx<8>(v));
    else if constexpr (M == 11) return lx<3>(lx<8>(v));
    else if constexpr (M == 12) return lx<3>(lx<15>(v));
    else if constexpr (M == 13) return lx<2>(lx<15>(v));
    else if constexpr (M == 14) return lx<1>(lx<15>(v));
    else if constexpr (M < 32)
        return __int_as_float(__builtin_amdgcn_ds_swizzle(__float_as_int(v), (M << 10) | 0x1F));
    else
        return __shfl_xor(v, M, 64);
}

__device__ __forceinline__ v2f cmul(v2f a, v2f b) {
    v2f n; n.x = -a.y; n.y = a.y;
    return a.xx * b + n * b.yx;
}

// ====== generalized RY on TWO interleaved states (shared angles, ILP=2) ======
template<int LM, int RM, int LW, int RW>
__device__ __forceinline__ void ry_g2(v2f sa[16], v2f sb[16], int lane, float c, float s) {
    static_assert((LM | RM) != 0, "null mask");
    const float baseP = (__builtin_popcount((unsigned)(lane & LW)) & 1) ? s : -s;
    if constexpr (RM == 0) {
#pragma unroll
        for (int r = 0; r < 16; ++r) {
            v2f pa, pb;
            pa.x = lx<LM ? LM : 1>(sa[r].x); pa.y = lx<LM ? LM : 1>(sa[r].y);
            pb.x = lx<LM ? LM : 1>(sb[r].x); pb.y = lx<LM ? LM : 1>(sb[r].y);
            const float cB = (__builtin_popcount((unsigned)(r & RW)) & 1) ? -baseP : baseP;
            sa[r] = c * sa[r] + cB * pa;
            sb[r] = c * sb[r] + cB * pb;
        }
    } else {
        constexpr int PIV = RM & (-RM);
#pragma unroll
        for (int r = 0; r < 16; ++r) {
            if (r & PIV) continue;
            const int rb = r ^ RM;
            v2f eaA, ebA, eaB, ebB;
            if constexpr (LM != 0) {
                eaA.x = lx<LM ? LM : 1>(sa[r].x);  eaA.y = lx<LM ? LM : 1>(sa[r].y);
                ebA.x = lx<LM ? LM : 1>(sa[rb].x); ebA.y = lx<LM ? LM : 1>(sa[rb].y);
                eaB.x = lx<LM ? LM : 1>(sb[r].x);  eaB.y = lx<LM ? LM : 1>(sb[r].y);
                ebB.x = lx<LM ? LM : 1>(sb[rb].x); ebB.y = lx<LM ? LM : 1>(sb[rb].y);
            } else {
                eaA = sa[r]; ebA = sa[rb]; eaB = sb[r]; ebB = sb[rb];
            }
            const float cBa = (__builtin_popcount((unsigned)(r & RW)) & 1) ? -baseP : baseP;
            const float cBb = (__builtin_popcount((unsigned)(rb & RW)) & 1) ? -baseP : baseP;
            sa[r]  = c * sa[r]  + cBa * ebA;
            sa[rb] = c * sa[rb] + cBb * eaA;
            sb[r]  = c * sb[r]  + cBa * ebB;
            sb[rb] = c * sb[rb] + cBb * eaB;
        }
    }
}

// ====== generalized fused Z-diagonal at frame R^L, two states ======
template<int L>
__device__ __forceinline__ void diag_g2(v2f sa[16], v2f sb[16], int lane, const float* pl) {
    constexpr M10 W = (L == 1) ? RF : RF2;
    float G[16];
#pragma unroll
    for (int i = 0; i < 16; ++i) G[i] = 0.f;
#pragma unroll
    for (int q = 0; q < 10; ++q) {
        const int LWq = laneM(W.r[q]);
        const int RWq = regM(W.r[q]);
        const float hz = 0.5f * pl[10 + q];
        const float gq = (__builtin_popcount((unsigned)(lane & LWq)) & 1) ? hz : -hz;
        G[RWq] += gq;
    }
#pragma unroll
    for (int m = 1; m < 16; m <<= 1) {
#pragma unroll
        for (int r = 0; r < 16; ++r) {
            if (r & m) continue;
            const float a = G[r], bb = G[r | m];
            G[r] = a + bb;
            G[r | m] = a - bb;
        }
    }
#pragma unroll
    for (int r = 0; r < 16; ++r) {
        float sn, cs;
        __sincosf(G[r], &sn, &cs);
        v2f d; d.x = cs; d.y = sn;
        sa[r] = cmul(sa[r], d);
        sb[r] = cmul(sb[r], d);
    }
}

__device__ __forceinline__ float wht64(float v, int lane) {
    float t;
    t = lx<1>(v);  v = (lane & 1)  ? (t - v) : (v + t);
    t = lx<2>(v);  v = (lane & 2)  ? (t - v) : (v + t);
    t = lx<4>(v);  v = (lane & 4)  ? (t - v) : (v + t);
    t = lx<8>(v);  v = (lane & 8)  ? (t - v) : (v + t);
    t = lx<16>(v); v = (lane & 16) ? (t - v) : (v + t);
    t = lx<32>(v); v = (lane & 32) ? (t - v) : (v + t);
    return v;
}

// ====== encode one sample's product state (enc + full layer 0 folded) ======
__device__ __forceinline__ void encode_state(const float* xb, const float* p0,
                                             const float* czt, const float* szt,
                                             int lane, v2f st[16]) {
    float a[10], bb[10];
#pragma unroll
    for (int q = 0; q < 10; ++q)
        __sincosf(0.5f * (xb[q] + p0[q]), &bb[q], &a[q]);

    float R = 1.f;
    v2f P; P.x = 1.f; P.y = 0.f;
#pragma unroll
    for (int q = 0; q <= 5; ++q) {
        const int m = 1 << (5 - q);
        R *= (lane & m) ? bb[q] : a[q];
        v2f t; t.x = czt[q]; t.y = (lane & m) ? szt[q] : -szt[q];
        P = cmul(P, t);
    }
    v2f laneC = R * P;

    v2f u[4][2];
#pragma unroll
    for (int q = 6; q <= 9; ++q) {
        u[q - 6][0].x = a[q] * czt[q];  u[q - 6][0].y = -a[q] * szt[q];
        u[q - 6][1].x = bb[q] * czt[q]; u[q - 6][1].y =  bb[q] * szt[q];
    }
    v2f A2[4], B2[4];
#pragma unroll
    for (int k = 0; k < 4; ++k) {
        A2[k] = cmul(u[0][k >> 1], u[1][k & 1]);
        B2[k] = cmul(u[2][k >> 1], u[3][k & 1]);
    }
    v2f LA[4] = { cmul(laneC, A2[0]), cmul(laneC, A2[1]),
                  cmul(laneC, A2[2]), cmul(laneC, A2[3]) };
#pragma unroll
    for (int r = 0; r < 16; ++r) st[r] = cmul(LA[r >> 2], B2[r & 3]);
}

// ================= main kernel: one wave per TWO batch samples =================
// Stored label t: lane bits = qubits 0..5 (masks 32..1), reg bits = qubits
// 6..9 (masks 8..1). Rings frame-tracked (never applied). All angles/tables
// are sample-independent -> shared across the wave's two samples; the two
// state-update chains are independent -> ILP hides DPP/ds latency.
__global__ __launch_bounds__(256, 2)
void pqc_kernel(const float* __restrict__ x,
                const float* __restrict__ params,
                float* __restrict__ out, int B) {
    const int lane = threadIdx.x & 63;
    const int wid = threadIdx.x >> 6;
    const int b0 = blockIdx.x * 8 + wid * 2;   // this wave: samples b0, b0+1
    if (b0 >= B) return;

    const float* p0 = params;
    float czt[10], szt[10];
#pragma unroll
    for (int q = 0; q < 10; ++q)
        __sincosf(0.5f * p0[10 + q], &szt[q], &czt[q]);

    v2f sa[16], sb[16];
    encode_state(x + (long)b0 * NQ, p0, czt, szt, lane, sa);
    encode_state(x + (long)(b0 + 1) * NQ, p0, czt, szt, lane, sb);
    // layer-0 ring virtual: F = R from here

#define GATE(INV, ROLE, Q, ANG) do { \
    float gc_, gs_; __sincosf(0.5f * (ANG), &gs_, &gc_); \
    ry_g2<laneM(colq(INV, Q)), regM(colq(INV, Q)), \
          laneM(ROLE.r[Q]), regM(ROLE.r[Q])>(sa, sb, lane, gc_, gs_); \
} while (0)

    // ---- layer 1 (frame F = R) ----
    {
        const float* pl = params + 20;
        GATE(RV, RF, 0, pl[0]); GATE(RV, RF, 1, pl[1]);
        GATE(RV, RF, 2, pl[2]); GATE(RV, RF, 3, pl[3]);
        GATE(RV, RF, 4, pl[4]); GATE(RV, RF, 5, pl[5]);
        GATE(RV, RF, 6, pl[6]); GATE(RV, RF, 7, pl[7]);
        GATE(RV, RF, 8, pl[8]); GATE(RV, RF, 9, pl[9]);
        diag_g2<1>(sa, sb, lane, pl);
    }
    // ---- layer 2 (frame F = R^2) ----
    {
        const float* pl = params + 40;
        GATE(RV2, RF2, 0, pl[0]); GATE(RV2, RF2, 1, pl[1]);
        GATE(RV2, RF2, 2, pl[2]); GATE(RV2, RF2, 3, pl[3]);
        GATE(RV2, RF2, 4, pl[4]); GATE(RV2, RF2, 5, pl[5]);
        GATE(RV2, RF2, 6, pl[6]); GATE(RV2, RF2, 7, pl[7]);
        GATE(RV2, RF2, 8, pl[8]); GATE(RV2, RF2, 9, pl[9]);
        diag_g2<2>(sa, sb, lane, pl);
    }
    // ---- layer 3 (frame F = R^3; diag+final ring fold into readout) ----
    {
        const float* pl = params + 60;
        GATE(RV3, RF3, 0, pl[0]); GATE(RV3, RF3, 1, pl[1]);
        GATE(RV3, RF3, 2, pl[2]); GATE(RV3, RF3, 3, pl[3]);
        GATE(RV3, RF3, 4, pl[4]); GATE(RV3, RF3, 5, pl[5]);
        GATE(RV3, RF3, 6, pl[6]); GATE(RV3, RF3, 7, pl[7]);
        GATE(RV3, RF3, 8, pl[8]); GATE(RV3, RF3, 9, pl[9]);
    }
#undef GATE

    // ---- readout: <Z_q> with roles = rows of R^4 ----
    float pA[16], pB[16];
#pragma unroll
    for (int r = 0; r < 16; ++r) {
        pA[r] = sa[r].x * sa[r].x + sa[r].y * sa[r].y;
        pB[r] = sb[r].x * sb[r].x + sb[r].y * sb[r].y;
    }
#pragma unroll
    for (int m = 1; m < 16; m <<= 1) {
#pragma unroll
        for (int r = 0; r < 16; ++r) {
            if (r & m) continue;
            const float a1 = pA[r], b1 = pA[r | m];
            pA[r] = a1 + b1; pA[r | m] = a1 - b1;
            const float a2 = pB[r], b2 = pB[r | m];
            pB[r] = a2 + b2; pB[r | m] = a2 - b2;
        }
    }
    const long baseA = (long)b0 * NQ;
    const long baseB = (long)(b0 + 1) * NQ;
#pragma unroll
    for (int q = 0; q < 10; ++q) {
        const int LWq = laneM(RF4.r[q]);
        const int RWq = regM(RF4.r[q]);
        const float vA = wht64(pA[RWq], lane);
        const float vB = wht64(pB[RWq], lane);
        if (lane == LWq) {
            out[baseA + q] = vA;
            out[baseB + q] = vB;
        }
    }
}

extern "C" void kernel_launch(void* const* d_in, const int* in_sizes, int n_in,
                              void* d_out, int out_size, void* d_ws, size_t ws_size,
                              hipStream_t stream) {
    const float* x = (const float*)d_in[0];       // [B, 10]
    const float* params = (const float*)d_in[1];  // [4, 20]
    float* out = (float*)d_out;                   // [B, 10]
    const int B = in_sizes[0] / NQ;               // 4096
    const int grid = (B + 7) / 8;                 // 4 waves/block, 2 samples/wave
    pqc_kernel<<<grid, 256, 0, stream>>>(x, params, out, B);
}